// Round 3
// baseline (2259.133 us; speedup 1.0000x reference)
//
#include <hip/hip_runtime.h>

// LightGCN propagation: 3 sparse layers over a fixed bipartite graph.
// R3: replace the random-scatter CSR build (8x write amplification, 620MB
// writes for an 80MB array) with a two-pass multisplit:
//   pass1: block-local split into 74 coarse buckets (row>>12), coalesced writes
//   pass2: counting-sort within bucket; dest stays in the ~1.1MB L2-resident
//          bucket region the read cursor is sweeping.

#define EMB 64
#define CHUNK 4096
#define SH 12          // bucket = row >> 12 -> 74 buckets for N=300001
#define MAXB 128

__global__ void hist_kernel(const int* __restrict__ rows, int* __restrict__ cnt, int nnz) {
    int i = blockIdx.x * blockDim.x + threadIdx.x;
    if (i < nnz) atomicAdd(&cnt[rows[i]], 1);
}

// ---- 3-kernel exclusive scan over M=N+1 counts (2048 elems / block) ----
__global__ void scan1(const int* __restrict__ cnt, int* __restrict__ bsum, int M) {
    __shared__ int s[256];
    int tid  = threadIdx.x;
    int base = blockIdx.x * 2048 + tid * 8;
    int t = 0;
#pragma unroll
    for (int j = 0; j < 8; ++j) { int i = base + j; if (i < M) t += cnt[i]; }
    s[tid] = t; __syncthreads();
    for (int off = 128; off > 0; off >>= 1) {
        if (tid < off) s[tid] += s[tid + off];
        __syncthreads();
    }
    if (tid == 0) bsum[blockIdx.x] = s[0];
}

// single block; requires nb <= 256 (here nb = ceil(300002/2048) = 147)
__global__ void scan2(int* bsum, int nb) {
    __shared__ int s[256];
    int tid = threadIdx.x;
    int x = (tid < nb) ? bsum[tid] : 0;
    int orig = x;
    s[tid] = x; __syncthreads();
    for (int off = 1; off < 256; off <<= 1) {
        int y = (tid >= off) ? s[tid - off] : 0;
        __syncthreads();
        x += y; s[tid] = x; __syncthreads();
    }
    if (tid < nb) bsum[tid] = x - orig;   // exclusive
}

__global__ void scan3(const int* __restrict__ cnt, const int* __restrict__ bsum,
                      int* __restrict__ row_ptr, int* __restrict__ cursor, int M) {
    __shared__ int s[256];
    int tid  = threadIdx.x;
    int base = blockIdx.x * 2048 + tid * 8;
    int v[8]; int t = 0;
#pragma unroll
    for (int j = 0; j < 8; ++j) { int i = base + j; v[j] = (i < M) ? cnt[i] : 0; t += v[j]; }
    int x = t;
    s[tid] = x; __syncthreads();
    for (int off = 1; off < 256; off <<= 1) {
        int y = (tid >= off) ? s[tid - off] : 0;
        __syncthreads();
        x += y; s[tid] = x; __syncthreads();
    }
    int run = bsum[blockIdx.x] + (x - t);   // exclusive prefix for this thread
#pragma unroll
    for (int j = 0; j < 8; ++j) {
        int i = base + j;
        if (i < M) {
            row_ptr[i] = run;
            if (i < M - 1) cursor[i] = run;  // cursor has N entries
        }
        run += v[j];
    }
}

// bucket b's CSR region starts at row_ptr[b << SH]
__global__ void bucket_init(const int* __restrict__ row_ptr, int* __restrict__ bucket_cursor,
                            int N, int nb) {
    int b = blockIdx.x * blockDim.x + threadIdx.x;
    if (b < nb) {
        int r = b << SH;
        bucket_cursor[b] = row_ptr[r < N ? r : N];
    }
}

// multisplit pass 1: group edges by coarse bucket with coalesced writes.
__global__ __launch_bounds__(256) void pass1_kernel(
    const int* __restrict__ rows, const int* __restrict__ cols,
    const float* __restrict__ vals, int* __restrict__ bucket_cursor,
    int* __restrict__ orow, int2* __restrict__ ocolval, int nnz)
{
    __shared__ int srow[CHUNK];
    __shared__ int hist[MAXB];
    __shared__ int base[MAXB];
    int tid   = threadIdx.x;
    int start = blockIdx.x * CHUNK;
    int end   = start + CHUNK; if (end > nnz) end = nnz;
    int cnt   = end - start;

    if (tid < MAXB) hist[tid] = 0;
    __syncthreads();
    for (int j = tid; j < cnt; j += 256) {
        int r = rows[start + j];
        srow[j] = r;
        atomicAdd(&hist[r >> SH], 1);
    }
    __syncthreads();
    if (tid < MAXB) {
        int h = hist[tid];
        base[tid] = h ? atomicAdd(&bucket_cursor[tid], h) : 0;
        hist[tid] = 0;
    }
    __syncthreads();
    for (int j = tid; j < cnt; j += 256) {
        int r  = srow[j];
        int b  = r >> SH;
        int rk = atomicAdd(&hist[b], 1);
        int d  = base[b] + rk;
        orow[d]    = r;
        ocolval[d] = make_int2(cols[start + j], __float_as_int(vals[start + j]));
    }
}

// multisplit pass 2: counting-sort scatter, destination within the same
// ~1.1MB bucket region as the (sequential) read position -> L2-absorbed.
__global__ __launch_bounds__(256) void pass2_kernel(
    const int* __restrict__ orow, const int2* __restrict__ ocolval,
    int* __restrict__ cursor, int2* __restrict__ edges, int nnz)
{
    int i = blockIdx.x * blockDim.x + threadIdx.x;
    if (i >= nnz) return;
    int r = orow[i];
    int p = atomicAdd(&cursor[r], 1);
    edges[p] = ocolval[i];
}

__device__ __forceinline__ const float* col_ptr(int c, const float* ue, const float* ie, int nu) {
    return (c < nu) ? (ue + (size_t)c * EMB) : (ie + ((size_t)c - nu) * EMB);
}

// One wave per row; lane = dim. Unrolled x8 for MLP.
// MODE 0: first layer (reads ue/ie directly, inits acc = e0 + sum)
// MODE 1: middle layer (acc += sum)
// MODE 2: last layer   (acc = (acc + sum) * 0.25, no embout write)
template<int MODE>
__global__ __launch_bounds__(256) void layer_kernel(
    const int* __restrict__ row_ptr, const int2* __restrict__ edges,
    const float* __restrict__ embin, const float* __restrict__ ue,
    const float* __restrict__ ie, float* __restrict__ embout,
    float* __restrict__ acc, int N, int nu)
{
    int row  = (int)((blockIdx.x * blockDim.x + threadIdx.x) >> 6);
    int lane = threadIdx.x & 63;
    if (row >= N) return;
    int s = row_ptr[row], e = row_ptr[row + 1];
    float sum0 = 0.f, sum1 = 0.f, sum2 = 0.f, sum3 = 0.f;
    int i = s;
    for (; i + 8 <= e; i += 8) {
        int2 c0 = edges[i+0], c1 = edges[i+1], c2 = edges[i+2], c3 = edges[i+3];
        int2 c4 = edges[i+4], c5 = edges[i+5], c6 = edges[i+6], c7 = edges[i+7];
        float g0, g1, g2, g3, g4, g5, g6, g7;
        if (MODE == 0) {
            g0 = col_ptr(c0.x, ue, ie, nu)[lane];
            g1 = col_ptr(c1.x, ue, ie, nu)[lane];
            g2 = col_ptr(c2.x, ue, ie, nu)[lane];
            g3 = col_ptr(c3.x, ue, ie, nu)[lane];
            g4 = col_ptr(c4.x, ue, ie, nu)[lane];
            g5 = col_ptr(c5.x, ue, ie, nu)[lane];
            g6 = col_ptr(c6.x, ue, ie, nu)[lane];
            g7 = col_ptr(c7.x, ue, ie, nu)[lane];
        } else {
            g0 = embin[(size_t)c0.x * EMB + lane];
            g1 = embin[(size_t)c1.x * EMB + lane];
            g2 = embin[(size_t)c2.x * EMB + lane];
            g3 = embin[(size_t)c3.x * EMB + lane];
            g4 = embin[(size_t)c4.x * EMB + lane];
            g5 = embin[(size_t)c5.x * EMB + lane];
            g6 = embin[(size_t)c6.x * EMB + lane];
            g7 = embin[(size_t)c7.x * EMB + lane];
        }
        sum0 = fmaf(__int_as_float(c0.y), g0, sum0);
        sum1 = fmaf(__int_as_float(c1.y), g1, sum1);
        sum2 = fmaf(__int_as_float(c2.y), g2, sum2);
        sum3 = fmaf(__int_as_float(c3.y), g3, sum3);
        sum0 = fmaf(__int_as_float(c4.y), g4, sum0);
        sum1 = fmaf(__int_as_float(c5.y), g5, sum1);
        sum2 = fmaf(__int_as_float(c6.y), g6, sum2);
        sum3 = fmaf(__int_as_float(c7.y), g7, sum3);
    }
    for (; i < e; ++i) {
        int2 cv = edges[i];
        float g = (MODE == 0) ? col_ptr(cv.x, ue, ie, nu)[lane]
                              : embin[(size_t)cv.x * EMB + lane];
        sum0 = fmaf(__int_as_float(cv.y), g, sum0);
    }
    float sum = (sum0 + sum1) + (sum2 + sum3);
    size_t idx = (size_t)row * EMB + lane;
    if (MODE != 2) embout[idx] = sum;
    if (MODE == 0) {
        float base = (row < nu) ? ue[idx] : ie[idx - (size_t)nu * EMB];
        acc[idx] = base + sum;
    } else if (MODE == 1) {
        acc[idx] += sum;
    } else {
        acc[idx] = (acc[idx] + sum) * 0.25f;
    }
}

extern "C" void kernel_launch(void* const* d_in, const int* in_sizes, int n_in,
                              void* d_out, int out_size, void* d_ws, size_t ws_size,
                              hipStream_t stream) {
    const float* ue   = (const float*)d_in[0];
    const float* ie   = (const float*)d_in[1];
    const float* vals = (const float*)d_in[2];
    const int*   rows = (const int*)d_in[3];
    const int*   cols = (const int*)d_in[4];

    int nu  = in_sizes[0] / EMB;
    int ni  = in_sizes[1] / EMB;
    int N   = nu + ni;
    int nnz = in_sizes[2];
    int M   = N + 1;
    int nb  = (N + (1 << SH) - 1) >> SH;   // 74 buckets

    // workspace carve-out (256B aligned).
    // Aliasing: orow+ocolval (pass-1 staging, 120MB) share the region with
    // embA+embB (153.6MB) — staging is dead before layer0 touches embA.
    char*  w   = (char*)d_ws;
    size_t off = 0;
    auto alloc = [&](size_t bytes) -> void* {
        void* p = w + off;
        off = (off + bytes + 255) & ~(size_t)255;
        return p;
    };
    size_t embBytes = (size_t)N * EMB * sizeof(float);
    char*  region0  = (char*)alloc(2 * embBytes);         // embA | embB  /  orow | ocolval
    float* embA     = (float*)region0;
    float* embB     = (float*)(region0 + embBytes);
    int*   orow     = (int*)region0;
    int2*  ocolval  = (int2*)(region0 + (((size_t)nnz * sizeof(int) + 255) & ~(size_t)255));
    int2*  edges    = (int2*) alloc((size_t)nnz * sizeof(int2));
    int*   cnt      = (int*)  alloc((size_t)M * sizeof(int));
    int*   row_ptr  = (int*)  alloc((size_t)M * sizeof(int));
    int*   cursor   = (int*)  alloc((size_t)N * sizeof(int));
    int*   bsum     = (int*)  alloc(1024 * sizeof(int));
    int*   bucket_cursor = (int*)alloc(MAXB * sizeof(int));
    float* acc      = (float*)d_out;   // accumulator lives in the output buffer

    hipMemsetAsync(cnt, 0, (size_t)M * sizeof(int), stream);

    hist_kernel<<<(nnz + 255) / 256, 256, 0, stream>>>(rows, cnt, nnz);

    int nsb = (M + 2047) / 2048;
    scan1<<<nsb, 256, 0, stream>>>(cnt, bsum, M);
    scan2<<<1,   256, 0, stream>>>(bsum, nsb);
    scan3<<<nsb, 256, 0, stream>>>(cnt, bsum, row_ptr, cursor, M);

    bucket_init<<<1, 128, 0, stream>>>(row_ptr, bucket_cursor, N, nb);

    int p1grid = (nnz + CHUNK - 1) / CHUNK;
    pass1_kernel<<<p1grid, 256, 0, stream>>>(rows, cols, vals, bucket_cursor, orow, ocolval, nnz);
    pass2_kernel<<<(nnz + 255) / 256, 256, 0, stream>>>(orow, ocolval, cursor, edges, nnz);

    int lgrid = (N + 3) / 4;   // 4 waves (rows) per 256-thread block
    layer_kernel<0><<<lgrid, 256, 0, stream>>>(row_ptr, edges, nullptr, ue, ie, embA, acc, N, nu);
    layer_kernel<1><<<lgrid, 256, 0, stream>>>(row_ptr, edges, embA, ue, ie, embB, acc, N, nu);
    layer_kernel<2><<<lgrid, 256, 0, stream>>>(row_ptr, edges, embB, ue, ie, nullptr, acc, N, nu);
}